// Round 1
// baseline (743.315 us; speedup 1.0000x reference)
//
#include <hip/hip_runtime.h>
#include <math.h>

// Problem constants
#define Bn   32
#define Hn   112
#define Wn   112
#define Cn   256
#define HWn  (Hn * Wn)      // 12544 spatial positions
#define C4   (Cn / 4)       // 64 float4 per position
#define HIDn 32
#define NB1  32             // pooling chunks per batch
#define POSB (HWn / NB1)    // 392 positions per pool block
#define NB3  98             // scale chunks per batch
#define POS3 (HWn / NB3)    // 128 positions per scale block

typedef float f4 __attribute__((ext_vector_type(4)));

// ---------------------------------------------------------------------------
// Kernel 1: partial sum/max pooling over spatial chunks.
// grid (NB1, Bn), block 256. lane c4 = tid&63 owns channels 4*c4..4*c4+3,
// group = tid>>6 strides over spatial positions. 64 lanes x 16B = 1KB/wave
// fully coalesced reads. Normal (caching) loads on purpose: the tail of this
// stream stays L3-resident for the scale pass.
// ---------------------------------------------------------------------------
__global__ __launch_bounds__(256) void pool_kernel(
    const f4* __restrict__ x4,
    float* __restrict__ psum,   // [Bn][NB1][Cn]
    float* __restrict__ pmax)   // [Bn][NB1][Cn]
{
    const int b   = blockIdx.y;
    const int blk = blockIdx.x;
    const int tid = threadIdx.x;
    const int c4  = tid & 63;
    const int grp = tid >> 6;   // 0..3

    const f4* base = x4 + ((size_t)b * HWn + (size_t)blk * POSB) * C4;

    f4 s = {0.f, 0.f, 0.f, 0.f};
    f4 m = {-3.402823466e38f, -3.402823466e38f,
            -3.402823466e38f, -3.402823466e38f};

    // 392/4 = 98 iterations per thread; compiler unrolls (trip count const)
    #pragma unroll 2
    for (int p = grp; p < POSB; p += 4) {
        f4 v = base[(size_t)p * C4 + c4];
        s += v;
        m.x = fmaxf(m.x, v.x); m.y = fmaxf(m.y, v.y);
        m.z = fmaxf(m.z, v.z); m.w = fmaxf(m.w, v.w);
    }

    __shared__ f4 ls[256];
    __shared__ f4 lm[256];
    ls[tid] = s;
    lm[tid] = m;
    __syncthreads();

    if (tid < 64) {
        f4 s0 = ls[tid], s1 = ls[tid + 64], s2 = ls[tid + 128], s3 = ls[tid + 192];
        f4 m0 = lm[tid], m1 = lm[tid + 64], m2 = lm[tid + 128], m3 = lm[tid + 192];
        f4 so = (s0 + s1) + (s2 + s3);
        f4 mo;
        mo.x = fmaxf(fmaxf(m0.x, m1.x), fmaxf(m2.x, m3.x));
        mo.y = fmaxf(fmaxf(m0.y, m1.y), fmaxf(m2.y, m3.y));
        mo.z = fmaxf(fmaxf(m0.z, m1.z), fmaxf(m2.z, m3.z));
        mo.w = fmaxf(fmaxf(m0.w, m1.w), fmaxf(m2.w, m3.w));
        f4* ps4 = (f4*)(psum + ((size_t)b * NB1 + blk) * Cn);
        f4* pm4 = (f4*)(pmax + ((size_t)b * NB1 + blk) * Cn);
        // partials are tiny and only re-read once by kernel 2 — keep them
        // out of the way of x with nontemporal stores
        __builtin_nontemporal_store(so, &ps4[tid]);
        __builtin_nontemporal_store(mo, &pm4[tid]);
    }
}

// ---------------------------------------------------------------------------
// Kernel 2: finish reduction + MLP + sigmoid. One block per batch, 256 threads.
// Reference does sigmoid(mlp(avg) + mlp(max)) -> b2 contributes TWICE.
// Since the second layer is linear: (h_a + h_m) @ w2 + 2*b2.
// ---------------------------------------------------------------------------
__global__ __launch_bounds__(256) void mlp_kernel(
    const float* __restrict__ psum,
    const float* __restrict__ pmax,
    const float* __restrict__ w1,   // [Cn][HIDn]
    const float* __restrict__ b1,   // [HIDn]
    const float* __restrict__ w2,   // [HIDn][Cn]
    const float* __restrict__ b2,   // [Cn]
    float* __restrict__ scale)      // [Bn][Cn]
{
    const int b   = blockIdx.x;
    const int tid = threadIdx.x;    // channel index

    __shared__ float avg[Cn];
    __shared__ float mx[Cn];
    __shared__ float h2[2][HIDn];

    float s = 0.f;
    float m = -3.402823466e38f;
    for (int k = 0; k < NB1; ++k) {
        s += psum[((size_t)b * NB1 + k) * Cn + tid];
        m = fmaxf(m, pmax[((size_t)b * NB1 + k) * Cn + tid]);
    }
    avg[tid] = s * (1.0f / (float)HWn);
    mx[tid]  = m;
    __syncthreads();

    if (tid < 64) {
        const int j = tid & 31;
        const int which = tid >> 5;              // 0 = avg, 1 = max
        const float* pool = which ? mx : avg;
        float acc = b1[j];
        for (int c = 0; c < Cn; ++c)
            acc += pool[c] * w1[c * HIDn + j];
        h2[which][j] = fmaxf(acc, 0.f);          // relu
    }
    __syncthreads();

    float acc = 2.0f * b2[tid];
    for (int j = 0; j < HIDn; ++j)
        acc += (h2[0][j] + h2[1][j]) * w2[j * Cn + tid];
    scale[(size_t)b * Cn + tid] = 1.0f / (1.0f + expf(-acc));
}

// ---------------------------------------------------------------------------
// Kernel 3: out = x * scale[b,c]. grid (NB3, Bn), block 256.
// REVERSED chunk order: the pool pass streamed x ascending, so the highest
// addresses are what's left in the 256 MB L3 — start there to convert the
// front of this pass's reads into L3 hits.
// Nontemporal stores: out is write-once/never-read; keep it from evicting x.
// ---------------------------------------------------------------------------
__global__ __launch_bounds__(256) void scale_kernel(
    const f4* __restrict__ x4,
    const float* __restrict__ scale,
    f4* __restrict__ out4)
{
    const int b   = (Bn - 1)  - (int)blockIdx.y;
    const int blk = (NB3 - 1) - (int)blockIdx.x;
    const int tid = threadIdx.x;
    const int c4  = tid & 63;
    const int grp = tid >> 6;

    const f4 sc = ((const f4*)(scale + (size_t)b * Cn))[c4];

    const size_t base = ((size_t)b * HWn + (size_t)blk * POS3) * C4;

    // 128/4 = 32 iterations per thread
    #pragma unroll 4
    for (int p = grp; p < POS3; p += 4) {
        const size_t idx = base + (size_t)p * C4 + c4;
        f4 v = x4[idx];
        v *= sc;
        __builtin_nontemporal_store(v, &out4[idx]);
    }
}

extern "C" void kernel_launch(void* const* d_in, const int* in_sizes, int n_in,
                              void* d_out, int out_size, void* d_ws, size_t ws_size,
                              hipStream_t stream) {
    const float* x  = (const float*)d_in[0];
    const float* w1 = (const float*)d_in[1];
    const float* b1 = (const float*)d_in[2];
    const float* w2 = (const float*)d_in[3];
    const float* b2 = (const float*)d_in[4];
    float* out = (float*)d_out;

    // workspace layout: psum [Bn*NB1*Cn] | pmax [Bn*NB1*Cn] | scale [Bn*Cn]
    float* psum  = (float*)d_ws;
    float* pmax  = psum + (size_t)Bn * NB1 * Cn;
    float* scale = pmax + (size_t)Bn * NB1 * Cn;

    pool_kernel<<<dim3(NB1, Bn), 256, 0, stream>>>((const f4*)x, psum, pmax);
    mlp_kernel<<<Bn, 256, 0, stream>>>(psum, pmax, w1, b1, w2, b2, scale);
    scale_kernel<<<dim3(NB3, Bn), 256, 0, stream>>>((const f4*)x, scale, (f4*)out);
}